// Round 6
// baseline (1682.563 us; speedup 1.0000x reference)
//
#include <hip/hip_runtime.h>

namespace {

constexpr int B = 64;
constexpr int L = 2048;
constexpr int Q = 256;
constexpr int S = 26;
constexpr float EPS = 1e-16f;
constexpr size_t POST = (size_t)B * L * Q;  // loglik offset in d_out

typedef _Float16 h2 __attribute__((ext_vector_type(2)));
typedef _Float16 f16x8 __attribute__((ext_vector_type(8)));
typedef float f32x4 __attribute__((ext_vector_type(4)));

#define MFMA16(a, b, c) __builtin_amdgcn_mfma_f32_16x16x32_f16((a), (b), (c), 0, 0, 0)

struct Smem {
  alignas(16) _Float16 vb[2][Q];     // scaled linear recursion vector (f16), dbuf
  alignas(16) _Float16 rowh[2][32];  // staged input row, f16 hi part (padded 26->32)
  alignas(16) _Float16 rowl[2][32];  // f16 lo residual part
  float sh[2];                       // state-0 anchor broadcast (f32), dbuf
  alignas(16) float afin[Q];         // final alpha for exact loglik
};

// LDS-only rendezvous: drain lgkm (covers LDS reads AND writes) but leave
// global loads/stores in flight across the barrier.
__device__ __forceinline__ void lds_barrier() {
  asm volatile("s_waitcnt lgkmcnt(0)\n\ts_barrier" ::: "memory");
}

__device__ __forceinline__ float wave_max64(float x) {
#pragma unroll
  for (int off = 32; off > 0; off >>= 1) x = fmaxf(x, __shfl_xor(x, off, 64));
  return x;
}
__device__ __forceinline__ float wave_sum64(float x) {
#pragma unroll
  for (int off = 32; off > 0; off >>= 1) x += __shfl_xor(x, off, 64);
  return x;
}

// Emission B-operand frags: expB^T[s][state], hi/lo split for ~f32 accuracy.
// B-frag layout (16x16x32): lane l holds B[(l>>4)*8 + j][l&15], j=0..7.
__device__ __forceinline__ void load_emit_frags(const float* __restrict__ log_B,
                                                int c0, int c1, int g, int q,
                                                f16x8& Bh0, f16x8& Bl0,
                                                f16x8& Bh1, f16x8& Bl1) {
#pragma unroll
  for (int j = 0; j < 8; ++j) {
    const int s = g * 8 + j;
    const float v0 = (s < S) ? __expf(log_B[(size_t)(c0 + q) * S + s]) : 0.f;
    const float v1 = (s < S) ? __expf(log_B[(size_t)(c1 + q) * S + s]) : 0.f;
    const _Float16 h0 = (_Float16)v0, h1 = (_Float16)v1;
    Bh0[j] = h0; Bl0[j] = (_Float16)(v0 - (float)h0);
    Bh1[j] = h1; Bl1[j] = (_Float16)(v1 - (float)h1);
  }
}

// Stage one input row (26 f32) into LDS as f16 hi + f16 residual, padded to
// 32. Called by wave 0, lanes 0..15 (lanes 13..15 write zero pad).
__device__ __forceinline__ void stage_row(Smem& sm, int buf, int lane, float2 gg) {
  _Float16 ah = (_Float16)0.f, bh = (_Float16)0.f;
  _Float16 al = (_Float16)0.f, bl = (_Float16)0.f;
  if (lane < 13) {
    ah = (_Float16)gg.x; bh = (_Float16)gg.y;
    al = (_Float16)(gg.x - (float)ah);
    bl = (_Float16)(gg.y - (float)bh);
  }
  ((h2*)sm.rowh[buf])[lane] = h2{ah, bh};
  ((h2*)sm.rowl[buf])[lane] = h2{al, bl};
}

// Direct per-lane load of one row slice (init only; 8 floats, 8B aligned).
__device__ __forceinline__ void load_row(const float2* __restrict__ r2, int g,
                                         bool rdl, float2* ld) {
  if (rdl) {
    const float2* p = r2 + g * 4;
    ld[0] = p[0];
    if (g < 3) { ld[1] = p[1]; ld[2] = p[2]; ld[3] = p[3]; }
  }
}

// Convert a row slice to hi/lo f16 A-frags (init only; non-participating
// lanes hold zeros, harmless for the D-row-0 trick).
__device__ __forceinline__ void cvt_row(const float2* ld, f16x8& xh, f16x8& xl) {
#pragma unroll
  for (int i = 0; i < 4; ++i) {
    const float a = ld[i].x, bb = ld[i].y;
    const _Float16 ah = (_Float16)a, bh = (_Float16)bb;
    xh[2 * i] = ah;     xl[2 * i] = (_Float16)(a - (float)ah);
    xh[2 * i + 1] = bh; xl[2 * i + 1] = (_Float16)(bb - (float)bh);
  }
}

// emit = (xh+xl) . (Bh+Bl) ~= xh*Bl + xl*Bh + xh*Bh  (3-term, ~f32 accurate)
__device__ __forceinline__ void emit_mfma(const f16x8& xh, const f16x8& xl,
                                          const f16x8& Bh0, const f16x8& Bl0,
                                          const f16x8& Bh1, const f16x8& Bl1,
                                          f32x4& E0, f32x4& E1) {
  const f32x4 Z = {0.f, 0.f, 0.f, 0.f};
  E0 = MFMA16(xh, Bl0, Z);
  E0 = MFMA16(xl, Bh0, E0);
  E0 = MFMA16(xh, Bh0, E0);
  E1 = MFMA16(xh, Bl1, Z);
  E1 = MFMA16(xl, Bh1, E1);
  E1 = MFMA16(xh, Bh1, E1);
}

// x = v^T * T, two 16-state tiles; K=256 as 8 frags, four 2-deep chains per
// tile (8 independent chains) to shorten the MFMA critical path. Only D row
// 0 (reg 0, lanes 0..15) is meaningful; garbage in A rows 1..15 cannot
// reach row 0.
__device__ __forceinline__ void matvec2(const f16x8* va, const f16x8* T0,
                                        const f16x8* T1, float& x0, float& x1) {
  const f32x4 Z = {0.f, 0.f, 0.f, 0.f};
  f32x4 a0 = MFMA16(va[0], T0[0], Z); a0 = MFMA16(va[1], T0[1], a0);
  f32x4 b0 = MFMA16(va[2], T0[2], Z); b0 = MFMA16(va[3], T0[3], b0);
  f32x4 c0 = MFMA16(va[4], T0[4], Z); c0 = MFMA16(va[5], T0[5], c0);
  f32x4 d0 = MFMA16(va[6], T0[6], Z); d0 = MFMA16(va[7], T0[7], d0);
  f32x4 a1 = MFMA16(va[0], T1[0], Z); a1 = MFMA16(va[1], T1[1], a1);
  f32x4 b1 = MFMA16(va[2], T1[2], Z); b1 = MFMA16(va[3], T1[3], b1);
  f32x4 c1 = MFMA16(va[4], T1[4], Z); c1 = MFMA16(va[5], T1[5], c1);
  f32x4 d1 = MFMA16(va[6], T1[6], Z); d1 = MFMA16(va[7], T1[7], d1);
  x0 = (a0[0] + b0[0]) + (c0[0] + d0[0]);
  x1 = (a1[0] + b1[0]) + (c1[0] + d1[0]);
}

// Sparse frag reads: only lanes with (lane&15)==0 carry A-operand data.
// xh/xl get row t+1 (for next-step emission); va gets the recursion vector.
__device__ __forceinline__ void read_frags(Smem& sm, int p, int g,
                                           f16x8& xh, f16x8& xl, f16x8* va) {
  xh = *(const f16x8*)(sm.rowh[p] + g * 8);
  xl = *(const f16x8*)(sm.rowl[p] + g * 8);
  const _Float16* vbp = sm.vb[p];
#pragma unroll
  for (int f = 0; f < 8; ++f) va[f] = *(const f16x8*)(vbp + f * 32 + g * 8);
}

// ---------------- forward ----------------
// Linear-space recursion with one-step-stale state-0 anchor (R4 anchor
// mechanics, unchanged). New: emission e_{t+1} is computed during step t
// from the staged row t+1 and held in registers, so step t's serial chain
// is only ds_read vb -> 2-deep matvec -> scale -> ds_write.
__device__ __forceinline__ void fwd_impl(int b, const float* __restrict__ inputs,
                                         const float* __restrict__ log_A,
                                         const float* __restrict__ log_pi,
                                         const float* __restrict__ log_B,
                                         float* __restrict__ out, Smem& sm) {
  const int tid = threadIdx.x, w = tid >> 6, lane = tid & 63;
  const int g = lane >> 4, q = lane & 15;
  const int c0 = w * 32, c1 = c0 + 16;
  const bool rdl = (q == 0);
  const bool epi = (lane < 16);
  const bool stg = (w == 0) && (lane < 16);

  // Static B-operand frags (persistent in VGPRs): T[k][c] = exp(log_A[k*Q+c]).
  f16x8 T0[8], T1[8];
#pragma unroll
  for (int f = 0; f < 8; ++f) {
#pragma unroll
    for (int j = 0; j < 8; ++j) {
      const int k = f * 32 + g * 8 + j;
      T0[f][j] = (_Float16)__expf(log_A[(size_t)k * Q + c0 + q]);
      T1[f][j] = (_Float16)__expf(log_A[(size_t)k * Q + c1 + q]);
    }
  }
  f16x8 Bh0, Bl0, Bh1, Bl1;
  load_emit_frags(log_B, c0, c1, g, q, Bh0, Bl0, Bh1, Bl1);

  const float2* __restrict__ inp2 = (const float2*)(inputs + (size_t)b * L * S);
  const float2* __restrict__ rlast = inp2 + (size_t)(L - 1) * 13;
  float* __restrict__ post_b = out + (size_t)b * L * Q;

  // ---- init: rows 0,1 direct; stage row 2 -> rowbuf[0]; hold row 3 ----
  float2 r0v[4] = {}, r1v[4] = {};
  load_row(inp2, g, rdl, r0v);
  load_row(inp2 + 13, g, rdl, r1v);
  float2 g2 = {0.f, 0.f}, gHold = {0.f, 0.f};
  if (w == 0 && lane < 13) { g2 = inp2[26 + lane]; gHold = inp2[39 + lane]; }
  if (stg) stage_row(sm, 0, lane, g2);

  f16x8 xh = {}, xl = {};
  cvt_row(r0v, xh, xl);
  f32x4 E0, E1;
  emit_mfma(xh, xl, Bh0, Bl0, Bh1, Bl1, E0, E1);  // e_0
  float eP0, eP1;
  {
    cvt_row(r1v, xh, xl);
    f32x4 F0, F1;
    emit_mfma(xh, xl, Bh0, Bl0, Bh1, Bl1, F0, F1);  // e_1
    eP0 = F0[0] + EPS; eP1 = F1[0] + EPS;
  }
  float zh0 = 1.f, zh1 = 1.f, rdp_h = 0.f;  // alpha_t = log(zh)+rdp_h, deferred
  if (epi) {
    zh0 = (E0[0] + EPS) * __expf(log_pi[c0 + lane]);
    zh1 = (E1[0] + EPS) * __expf(log_pi[c1 + lane]);
  }
  if (tid == 0) sm.sh[0] = __logf(zh0);  // alpha_0(0)
  __syncthreads();
  float rd_prev = sm.sh[0];
  if (epi) {
    const float sc = __expf(-rd_prev);
    sm.vb[0][c0 + lane] = (_Float16)(zh0 * sc);
    sm.vb[0][c1 + lane] = (_Float16)(zh1 * sc);
  }
  __syncthreads();

  f16x8 va[8];
#pragma unroll
  for (int f = 0; f < 8; ++f) va[f] = f16x8{};

  const float2* pin = inp2 + 4 * 13;  // row t+3 at t=1
  float* pb = post_b + c0 + lane;     // row t-1 store base
  int p = 0;
  for (int t = 1; t < L; ++t) {
    // stage row t+2 from regs held since step t-1 (no vmcnt stall)
    if (stg) stage_row(sm, p ^ 1, lane, gHold);
    const float rd = sm.sh[p];  // alpha_{t-1}(0)
    if (rdl) read_frags(sm, p, g, xh, xl, va);  // row t+1 frags + vb_{t-1}
    // issue load of row t+3
    float2 gN = gHold;
    if (w == 0 && lane < 13) gN = ((t + 3 < L) ? pin : rlast)[lane];
    pin += 13;
    // delayed store of alpha_{t-1} (log off the critical path)
    if (epi) {
      pb[0]  = __logf(zh0) + rdp_h;
      pb[16] = __logf(zh1) + rdp_h;
    }
    pb += Q;
    f32x4 F0_, F1_;
    emit_mfma(xh, xl, Bh0, Bl0, Bh1, Bl1, F0_, F1_);  // e_{t+1} (next step)
    float x0, x1;
    matvec2(va, T0, T1, x0, x1);
    const float gam = __expf(rd_prev - rd);
    if (epi) {
      const float z0 = x0 * eP0, z1 = x1 * eP1;
      sm.vb[p ^ 1][c0 + lane] = (_Float16)(z0 * gam);
      sm.vb[p ^ 1][c1 + lane] = (_Float16)(z1 * gam);
      if (tid == 0) sm.sh[p ^ 1] = __logf(z0) + rd_prev;  // alpha_t(0)
      zh0 = z0; zh1 = z1;
    }
    eP0 = F0_[0] + EPS; eP1 = F1_[0] + EPS;
    gHold = gN;
    rdp_h = rd_prev;
    rd_prev = rd;
    lds_barrier();
    p ^= 1;
  }

  // epilogue: final alpha store + exact loglik
  if (epi) {
    const float a0 = __logf(zh0) + rdp_h;
    const float a1 = __logf(zh1) + rdp_h;
    pb[0] = a0; pb[16] = a1;
    sm.afin[c0 + lane] = a0;
    sm.afin[c1 + lane] = a1;
  }
  __syncthreads();
  if (w == 0) {
    float4 fa = ((const float4*)sm.afin)[lane];
    float m = fmaxf(fmaxf(fa.x, fa.y), fmaxf(fa.z, fa.w));
    m = wave_max64(m);
    float ss = __expf(fa.x - m) + __expf(fa.y - m) + __expf(fa.z - m) + __expf(fa.w - m);
    ss = wave_sum64(ss);
    if (lane == 0) out[POST + b] = __logf(ss) + m;
  }
}

// ---------------- backward ----------------
// MODE 0: beta -> ws (concurrent with fwd). MODE 1: fused RMW post += beta - ll.
template <int MODE>
__device__ __forceinline__ void bwd_impl(int b, const float* __restrict__ inputs,
                                         const float* __restrict__ log_A,
                                         const float* __restrict__ log_B,
                                         float* __restrict__ out,
                                         float* __restrict__ ws, Smem& sm) {
  const int tid = threadIdx.x, w = tid >> 6, lane = tid & 63;
  const int g = lane >> 4, q = lane & 15;
  const int c0 = w * 32, c1 = c0 + 16;
  const bool rdl = (q == 0);
  const bool epi = (lane < 16);
  const bool stg = (w == 0) && (lane < 16);

  // bwd matvec is with A (not A^T): T[k][c] = exp(log_A[c*Q + k]).
  f16x8 T0[8], T1[8];
#pragma unroll
  for (int f = 0; f < 8; ++f) {
#pragma unroll
    for (int j = 0; j < 8; ++j) {
      const int k = f * 32 + g * 8 + j;
      T0[f][j] = (_Float16)__expf(log_A[(size_t)(c0 + q) * Q + k]);
      T1[f][j] = (_Float16)__expf(log_A[(size_t)(c1 + q) * Q + k]);
    }
  }
  f16x8 Bh0, Bl0, Bh1, Bl1;
  load_emit_frags(log_B, c0, c1, g, q, Bh0, Bl0, Bh1, Bl1);

  const float2* __restrict__ inp2 = (const float2*)(inputs + (size_t)b * L * S);
  float* __restrict__ post_b = out + (size_t)b * L * Q;
  float* __restrict__ ws_b = ws + (size_t)b * L * Q;

  float ll = 0.f, a_h0 = 0.f, a_h1 = 0.f;
  if (MODE == 1) {
    ll = out[POST + b];
    if (epi) {
      a_h0 = post_b[(size_t)(L - 1) * Q + c0 + lane];
      a_h1 = post_b[(size_t)(L - 1) * Q + c1 + lane];
    }
  }

  // ---- init: rows L-1,L-2 direct; stage row L-3 -> rowbuf[0]; hold L-4 ----
  float2 rAv[4] = {}, rBv[4] = {};
  load_row(inp2 + (size_t)(L - 1) * 13, g, rdl, rAv);
  load_row(inp2 + (size_t)(L - 2) * 13, g, rdl, rBv);
  float2 g2 = {0.f, 0.f}, gHold = {0.f, 0.f};
  if (w == 0 && lane < 13) {
    g2 = inp2[(size_t)(L - 3) * 13 + lane];
    gHold = inp2[(size_t)(L - 4) * 13 + lane];
  }
  if (stg) stage_row(sm, 0, lane, g2);

  f16x8 xh = {}, xl = {};
  cvt_row(rAv, xh, xl);
  f32x4 E0, E1;
  emit_mfma(xh, xl, Bh0, Bl0, Bh1, Bl1, E0, E1);  // e_{L-1}
  float eP0, eP1;
  {
    cvt_row(rBv, xh, xl);
    f32x4 F0, F1;
    emit_mfma(xh, xl, Bh0, Bl0, Bh1, Bl1, F0, F1);  // e_{L-2}
    eP0 = F0[0] + EPS; eP1 = F1[0] + EPS;
  }
  float e0i = 1.f, e1i = 1.f;
  if (epi) { e0i = E0[0] + EPS; e1i = E1[0] + EPS; }
  if (tid == 0) sm.sh[0] = __logf(e0i);  // u_{L-1}(0)
  __syncthreads();
  float rd_prev = sm.sh[0];
  if (epi) {
    const float sc = __expf(-rd_prev);
    sm.vb[0][c0 + lane] = (_Float16)(e0i * sc);
    sm.vb[0][c1 + lane] = (_Float16)(e1i * sc);
  }
  float rh0 = 1.f, rh1 = 1.f, rdp_h = 0.f;  // beta_{L-1} = 0
  __syncthreads();

  f16x8 va[8];
#pragma unroll
  for (int f = 0; f < 8; ++f) va[f] = f16x8{};

  const float2* pin = inp2 + (size_t)(L - 5) * 13;  // row t-3 at t=L-2
  float* wp = ws_b + (size_t)(L - 1) * Q + c0 + lane;
  float* pp = post_b + (size_t)(L - 1) * Q + c0 + lane;
  int p = 0;
  for (int t = L - 2; t >= 0; --t) {
    // stage row t-1 from regs held since last step
    if (stg) stage_row(sm, p ^ 1, lane, gHold);
    const float rd = sm.sh[p];
    if (rdl) read_frags(sm, p, g, xh, xl, va);  // row t-1 frags + vb_{t+1}
    // issue load of row t-3
    float2 gN = gHold;
    if (w == 0 && lane < 13) gN = ((t >= 3) ? pin : inp2)[lane];
    pin -= 13;
    if (epi) {  // delayed output for row t+1: beta = log(raw) + anchor
      const float b0 = __logf(rh0) + rdp_h;
      const float b1 = __logf(rh1) + rdp_h;
      if (MODE == 0) {
        wp[0] = b0; wp[16] = b1;
      } else {
        pp[0] = a_h0 + b0 - ll;
        pp[16] = a_h1 + b1 - ll;
        a_h0 = (pp - Q)[0];   // prefetch alpha_t
        a_h1 = (pp - Q)[16];
      }
    }
    wp -= Q; pp -= Q;
    f32x4 F0_, F1_;
    emit_mfma(xh, xl, Bh0, Bl0, Bh1, Bl1, F0_, F1_);  // e_{t-1} (next step)
    float r0, r1;
    matvec2(va, T0, T1, r0, r1);
    const float gam = __expf(rd_prev - rd);
    if (epi) {
      const float z0 = r0 * eP0, z1 = r1 * eP1;
      sm.vb[p ^ 1][c0 + lane] = (_Float16)(z0 * gam);
      sm.vb[p ^ 1][c1 + lane] = (_Float16)(z1 * gam);
      if (tid == 0) sm.sh[p ^ 1] = __logf(z0) + rd_prev;  // u_t(0)
      rh0 = r0; rh1 = r1;
    }
    eP0 = F0_[0] + EPS; eP1 = F1_[0] + EPS;
    gHold = gN;
    rdp_h = rd_prev;
    rd_prev = rd;
    lds_barrier();
    p ^= 1;
  }

  // epilogue: row 0
  if (epi) {
    const float b0 = __logf(rh0) + rdp_h;
    const float b1 = __logf(rh1) + rdp_h;
    if (MODE == 0) {
      wp[0] = b0; wp[16] = b1;
    } else {
      pp[0] = a_h0 + b0 - ll;
      pp[16] = a_h1 + b1 - ll;
    }
  }
}

// ---------------- kernels ----------------
__global__ __launch_bounds__(512, 2)
void hmm_fwdbwd(const float* __restrict__ inputs, const float* __restrict__ log_A,
                const float* __restrict__ log_pi, const float* __restrict__ log_B,
                float* __restrict__ out, float* __restrict__ ws) {
  __shared__ Smem sm;
  if (blockIdx.x < B) fwd_impl(blockIdx.x, inputs, log_A, log_pi, log_B, out, sm);
  else                bwd_impl<0>(blockIdx.x - B, inputs, log_A, log_B, out, ws, sm);
}

__global__ __launch_bounds__(256)
void hmm_combine(const float* __restrict__ ws, float* __restrict__ out) {
  const size_t idx = (size_t)blockIdx.x * 256 + threadIdx.x;  // float4 index
  const int b = (int)(idx >> 17);  // L*Q/4 = 131072 float4 per batch
  const float ll = out[POST + b];
  float4 a = ((const float4*)out)[idx];
  const float4 be = ((const float4*)ws)[idx];
  a.x += be.x - ll;
  a.y += be.y - ll;
  a.z += be.z - ll;
  a.w += be.w - ll;
  ((float4*)out)[idx] = a;
}

__global__ __launch_bounds__(512, 2)
void hmm_fwd_only(const float* __restrict__ inputs, const float* __restrict__ log_A,
                  const float* __restrict__ log_pi, const float* __restrict__ log_B,
                  float* __restrict__ out) {
  __shared__ Smem sm;
  fwd_impl(blockIdx.x, inputs, log_A, log_pi, log_B, out, sm);
}

__global__ __launch_bounds__(512, 2)
void hmm_bwd_fused(const float* __restrict__ inputs, const float* __restrict__ log_A,
                   const float* __restrict__ log_B, float* __restrict__ out) {
  __shared__ Smem sm;
  bwd_impl<1>(blockIdx.x, inputs, log_A, log_B, out, nullptr, sm);
}

}  // namespace

extern "C" void kernel_launch(void* const* d_in, const int* in_sizes, int n_in,
                              void* d_out, int out_size, void* d_ws, size_t ws_size,
                              hipStream_t stream) {
  const float* inputs = (const float*)d_in[0];
  const float* log_A  = (const float*)d_in[1];
  const float* log_pi = (const float*)d_in[2];
  const float* log_B  = (const float*)d_in[3];
  float* out = (float*)d_out;
  float* ws  = (float*)d_ws;

  if (ws_size >= POST * sizeof(float)) {
    hipLaunchKernelGGL(hmm_fwdbwd, dim3(2 * B), dim3(512), 0, stream,
                       inputs, log_A, log_pi, log_B, out, ws);
    hipLaunchKernelGGL(hmm_combine, dim3((unsigned)(POST / 4 / 256)), dim3(256), 0, stream,
                       ws, out);
  } else {
    hipLaunchKernelGGL(hmm_fwd_only, dim3(B), dim3(512), 0, stream,
                       inputs, log_A, log_pi, log_B, out);
    hipLaunchKernelGGL(hmm_bwd_fused, dim3(B), dim3(512), 0, stream,
                       inputs, log_A, log_B, out);
  }
}